// Round 5
// baseline (276.144 us; speedup 1.0000x reference)
//
#include <hip/hip_runtime.h>

// ContrastLoss: loss = -sum_i dot(f_s[i], f_t[i]) / B   (B=65536, D=512, fp32)
// diag(f_s @ f_t.T) is a row-wise dot -> pure streaming reduction over
// 2 x 128 MiB of fp32. Memory-bound; roofline ~43 us at 6.3 TB/s.
//
// Primary path: two-kernel deterministic reduce via d_ws partials.
// Fallback (ws_size too small): zero-init out + device-scope atomicAdd of
// block partials scaled by -1/B. Both paths do identical work every call
// (graph-capture safe; no mallocs/syncs).

#define RED_BLOCKS  2048
#define RED_THREADS 256

__device__ __forceinline__ float block_partial_dot(
        const float4* __restrict__ a, const float4* __restrict__ b, long n4) {
    long tid    = (long)blockIdx.x * blockDim.x + threadIdx.x;
    long stride = (long)gridDim.x * blockDim.x;

    float acc = 0.0f;
    long i = tid;
    for (; i + stride < n4; i += 2 * stride) {
        float4 x0 = a[i];
        float4 y0 = b[i];
        float4 x1 = a[i + stride];
        float4 y1 = b[i + stride];
        acc = fmaf(x0.x, y0.x, acc);
        acc = fmaf(x0.y, y0.y, acc);
        acc = fmaf(x0.z, y0.z, acc);
        acc = fmaf(x0.w, y0.w, acc);
        acc = fmaf(x1.x, y1.x, acc);
        acc = fmaf(x1.y, y1.y, acc);
        acc = fmaf(x1.z, y1.z, acc);
        acc = fmaf(x1.w, y1.w, acc);
    }
    for (; i < n4; i += stride) {
        float4 x = a[i];
        float4 y = b[i];
        acc = fmaf(x.x, y.x, acc);
        acc = fmaf(x.y, y.y, acc);
        acc = fmaf(x.z, y.z, acc);
        acc = fmaf(x.w, y.w, acc);
    }

    // wave-64 butterfly reduce
    #pragma unroll
    for (int off = 32; off > 0; off >>= 1)
        acc += __shfl_down(acc, off, 64);

    __shared__ float smem[RED_THREADS / 64];
    int lane = threadIdx.x & 63;
    int wave = threadIdx.x >> 6;
    if (lane == 0) smem[wave] = acc;
    __syncthreads();

    float s = 0.0f;
    if (threadIdx.x == 0) {
        #pragma unroll
        for (int w = 0; w < RED_THREADS / 64; ++w) s += smem[w];
    }
    return s;  // valid only on thread 0
}

__global__ __launch_bounds__(RED_THREADS) void
contrast_partial(const float4* __restrict__ a, const float4* __restrict__ b,
                 float* __restrict__ partials, long n4) {
    float s = block_partial_dot(a, b, n4);
    if (threadIdx.x == 0) partials[blockIdx.x] = s;
}

__global__ __launch_bounds__(RED_THREADS) void
contrast_finalize(const float* __restrict__ partials, float* __restrict__ out,
                  int np, float neg_inv_b) {
    float acc = 0.0f;
    for (int i = threadIdx.x; i < np; i += blockDim.x)
        acc += partials[i];

    #pragma unroll
    for (int off = 32; off > 0; off >>= 1)
        acc += __shfl_down(acc, off, 64);

    __shared__ float smem[RED_THREADS / 64];
    int lane = threadIdx.x & 63;
    int wave = threadIdx.x >> 6;
    if (lane == 0) smem[wave] = acc;
    __syncthreads();

    if (threadIdx.x == 0) {
        float s = 0.0f;
        #pragma unroll
        for (int w = 0; w < RED_THREADS / 64; ++w) s += smem[w];
        out[0] = s * neg_inv_b;   // -sum / B
    }
}

// ---- fallback path (no workspace): zero out, then atomicAdd partials ----
__global__ void contrast_zero(float* __restrict__ out) {
    out[0] = 0.0f;
}

__global__ __launch_bounds__(RED_THREADS) void
contrast_partial_atomic(const float4* __restrict__ a, const float4* __restrict__ b,
                        float* __restrict__ out, long n4, float neg_inv_b) {
    float s = block_partial_dot(a, b, n4);
    if (threadIdx.x == 0) atomicAdd(out, s * neg_inv_b);  // device-scope by default
}

extern "C" void kernel_launch(void* const* d_in, const int* in_sizes, int n_in,
                              void* d_out, int out_size, void* d_ws, size_t ws_size,
                              hipStream_t stream) {
    const float4* f_s = (const float4*)d_in[0];
    const float4* f_t = (const float4*)d_in[1];
    float* out = (float*)d_out;

    const long n  = (long)in_sizes[0];        // B*D = 33,554,432
    const long n4 = n / 4;                    // float4 count
    const long B  = n / 512;                  // D=512 per reference
    const float neg_inv_b = -1.0f / (float)B;

    if (d_ws != nullptr && ws_size >= RED_BLOCKS * sizeof(float)) {
        float* partials = (float*)d_ws;
        contrast_partial<<<RED_BLOCKS, RED_THREADS, 0, stream>>>(f_s, f_t, partials, n4);
        contrast_finalize<<<1, RED_THREADS, 0, stream>>>(partials, out, RED_BLOCKS,
                                                         neg_inv_b);
    } else {
        contrast_zero<<<1, 1, 0, stream>>>(out);
        contrast_partial_atomic<<<RED_BLOCKS, RED_THREADS, 0, stream>>>(f_s, f_t, out,
                                                                        n4, neg_inv_b);
    }
}